// Round 1
// baseline (5778.297 us; speedup 1.0000x reference)
//
#include <hip/hip_runtime.h>

#define NN 100000
#define EE 1600000
#define EPE 500000
// DIN = DH = 128, DOUT = 64

__global__ void count_deg_k(const int* __restrict__ dst, int* __restrict__ deg) {
    int t = blockIdx.x * 256 + threadIdx.x;
    if (t < EE) atomicAdd(&deg[dst[t]], 1);
}

__global__ void inv_deg_k(const int* __restrict__ deg, float* __restrict__ invd) {
    int t = blockIdx.x * 256 + threadIdx.x;
    if (t < NN) invd[t] = 1.0f / fmaxf((float)deg[t], 1.0f);
}

// One float4 (4 features) per thread; 32 threads cover a 128-wide edge row.
__global__ void scatter_add_k(const float4* __restrict__ feat, const int* __restrict__ src,
                              const int* __restrict__ dst, float* __restrict__ agg) {
    long long t = (long long)blockIdx.x * 256 + threadIdx.x;
    int e = (int)(t >> 5);
    int c = (int)(t & 31);
    if (e >= EE) return;
    int s = src[e], d = dst[e];
    float4 v = feat[(long long)s * 32 + c];
    float* o = agg + (long long)d * 128 + c * 4;
    atomicAdd(o + 0, v.x);
    atomicAdd(o + 1, v.y);
    atomicAdd(o + 2, v.z);
    atomicAdd(o + 3, v.w);
}

// h_out = act( [mean | h_in] @ [Wl ; Wr] + b ), input dim fixed at 128+128=256.
// Block: 64 rows x OUTD cols, 256 threads, each 4 rows x (OUTD/16) cols.
template<int OUTD, bool RELU>
__global__ __launch_bounds__(256) void gemm_sage_k(
    const float* __restrict__ agg, const float* __restrict__ invd,
    const float* __restrict__ hin, const float* __restrict__ Wl,
    const float* __restrict__ bl, const float* __restrict__ Wr,
    float* __restrict__ hout)
{
    constexpr int CPT = OUTD / 16;   // cols per thread: 8 (OUTD=128) or 4 (OUTD=64)
    constexpr int F4  = OUTD / 4;    // float4s per W row
    __shared__ float As[16][64];
    __shared__ float Ws[16][OUTD];

    const int tid = threadIdx.x;
    const int tx = tid & 15, ty = tid >> 4;
    const int row0 = blockIdx.x * 64;

    float acc[4][CPT];
    #pragma unroll
    for (int i = 0; i < 4; ++i)
        #pragma unroll
        for (int j = 0; j < CPT; ++j) acc[i][j] = 0.f;

    const int lr = tid >> 2;   // tile row for A staging (0..63)
    const int lq = tid & 3;    // which float4 of the 16-wide k-chunk
    const int grow = row0 + lr;
    const bool rvalid = grow < NN;
    const float inv = rvalid ? invd[grow] : 0.f;

    for (int kc = 0; kc < 16; ++kc) {
        // --- stage A chunk (64 rows x 16 k) ---
        float4 av = make_float4(0.f, 0.f, 0.f, 0.f);
        if (rvalid) {
            if (kc < 8) {  // mean half
                av = ((const float4*)agg)[(long long)grow * 32 + kc * 4 + lq];
                av.x *= inv; av.y *= inv; av.z *= inv; av.w *= inv;
            } else {       // self half
                av = ((const float4*)hin)[(long long)grow * 32 + (kc - 8) * 4 + lq];
            }
        }
        As[lq * 4 + 0][lr] = av.x;
        As[lq * 4 + 1][lr] = av.y;
        As[lq * 4 + 2][lr] = av.z;
        As[lq * 4 + 3][lr] = av.w;

        // --- stage W chunk (16 k x OUTD) ---
        #pragma unroll
        for (int m = 0; m < OUTD / 64; ++m) {
            int idx = tid + m * 256;
            int kk = idx / F4, f4 = idx % F4;
            int kg = kc * 16 + kk;
            float4 wv = (kg < 128) ? ((const float4*)Wl)[(long long)kg * F4 + f4]
                                   : ((const float4*)Wr)[(long long)(kg - 128) * F4 + f4];
            ((float4*)&Ws[kk][0])[f4] = wv;
        }
        __syncthreads();

        // --- compute ---
        #pragma unroll
        for (int kk = 0; kk < 16; ++kk) {
            float a0 = As[kk][ty];
            float a1 = As[kk][ty + 16];
            float a2 = As[kk][ty + 32];
            float a3 = As[kk][ty + 48];
            float w[CPT];
            #pragma unroll
            for (int j4 = 0; j4 < CPT / 4; ++j4) {
                float4 wv = ((const float4*)&Ws[kk][0])[tx * (CPT / 4) + j4];
                w[j4 * 4 + 0] = wv.x; w[j4 * 4 + 1] = wv.y;
                w[j4 * 4 + 2] = wv.z; w[j4 * 4 + 3] = wv.w;
            }
            #pragma unroll
            for (int j = 0; j < CPT; ++j) {
                acc[0][j] += a0 * w[j];
                acc[1][j] += a1 * w[j];
                acc[2][j] += a2 * w[j];
                acc[3][j] += a3 * w[j];
            }
        }
        __syncthreads();
    }

    // --- epilogue: bias (+ relu) + store ---
    #pragma unroll
    for (int i = 0; i < 4; ++i) {
        int r = row0 + ty + 16 * i;
        if (r < NN) {
            #pragma unroll
            for (int j4 = 0; j4 < CPT / 4; ++j4) {
                int c = tx * CPT + j4 * 4;
                float4 o;
                o.x = acc[i][j4 * 4 + 0] + bl[c + 0];
                o.y = acc[i][j4 * 4 + 1] + bl[c + 1];
                o.z = acc[i][j4 * 4 + 2] + bl[c + 2];
                o.w = acc[i][j4 * 4 + 3] + bl[c + 3];
                if (RELU) {
                    o.x = fmaxf(o.x, 0.f); o.y = fmaxf(o.y, 0.f);
                    o.z = fmaxf(o.z, 0.f); o.w = fmaxf(o.w, 0.f);
                }
                ((float4*)hout)[((long long)r * OUTD + c) >> 2] = o;
            }
        }
    }
}

// 16 lanes per scored edge; float4 per lane covers 64 dims.
__global__ void score_k(const float4* __restrict__ h2, const int* __restrict__ pos,
                        const int* __restrict__ neg, float* __restrict__ out) {
    int t = blockIdx.x * 256 + threadIdx.x;
    int eg = t >> 4, l = t & 15;
    if (eg >= 2 * EPE) return;
    int a, b;
    if (eg < EPE) { a = pos[eg]; b = pos[EPE + eg]; }
    else { int e2 = eg - EPE; a = neg[e2]; b = neg[EPE + e2]; }
    float4 va = h2[(long long)a * 16 + l];
    float4 vb = h2[(long long)b * 16 + l];
    float p = va.x * vb.x + va.y * vb.y + va.z * vb.z + va.w * vb.w;
    p += __shfl_xor(p, 1, 16);
    p += __shfl_xor(p, 2, 16);
    p += __shfl_xor(p, 4, 16);
    p += __shfl_xor(p, 8, 16);
    if (l == 0) out[eg] = p;
}

extern "C" void kernel_launch(void* const* d_in, const int* in_sizes, int n_in,
                              void* d_out, int out_size, void* d_ws, size_t ws_size,
                              hipStream_t stream) {
    const float* x   = (const float*)d_in[0];
    const int*   ei  = (const int*)d_in[1];
    const int*   pei = (const int*)d_in[2];
    const int*   nei = (const int*)d_in[3];
    const float* Wl0 = (const float*)d_in[4];
    const float* bl0 = (const float*)d_in[5];
    const float* Wr0 = (const float*)d_in[6];
    const float* Wl1 = (const float*)d_in[7];
    const float* bl1 = (const float*)d_in[8];
    const float* Wr1 = (const float*)d_in[9];
    float* out = (float*)d_out;

    char* ws = (char*)d_ws;
    size_t off = 0;
    auto alloc = [&](size_t bytes) {
        void* p = ws + off;
        off = (off + bytes + 255) & ~(size_t)255;
        return p;
    };
    int*   deg  = (int*)  alloc((size_t)NN * 4);
    float* invd = (float*)alloc((size_t)NN * 4);
    float* agg  = (float*)alloc((size_t)NN * 128 * 4);
    float* h1   = (float*)alloc((size_t)NN * 128 * 4);
    float* h2   = (float*)alloc((size_t)NN * 64 * 4);

    const int* src = ei;        // edge_index[0]
    const int* dst = ei + EE;   // edge_index[1]

    hipMemsetAsync(deg, 0, (size_t)NN * 4, stream);
    hipMemsetAsync(agg, 0, (size_t)NN * 128 * 4, stream);

    count_deg_k<<<(EE + 255) / 256, 256, 0, stream>>>(dst, deg);
    inv_deg_k<<<(NN + 255) / 256, 256, 0, stream>>>(deg, invd);

    // layer 0
    scatter_add_k<<<(int)(((long long)EE * 32) / 256), 256, 0, stream>>>((const float4*)x, src, dst, agg);
    gemm_sage_k<128, true><<<(NN + 63) / 64, 256, 0, stream>>>(agg, invd, x, Wl0, bl0, Wr0, h1);

    // layer 1
    hipMemsetAsync(agg, 0, (size_t)NN * 128 * 4, stream);
    scatter_add_k<<<(int)(((long long)EE * 32) / 256), 256, 0, stream>>>((const float4*)h1, src, dst, agg);
    gemm_sage_k<64, false><<<(NN + 63) / 64, 256, 0, stream>>>(agg, invd, h1, Wl1, bl1, Wr1, h2);

    // scoring
    score_k<<<(2 * EPE * 16 + 255) / 256, 256, 0, stream>>>((const float4*)h2, pei, nei, out);
}

// Round 2
// 750.075 us; speedup vs baseline: 7.7036x; 7.7036x over previous
//
#include <hip/hip_runtime.h>

#define NN 100000
#define EE 1600000
#define EPE 500000
#define NB_SCAN 391   // ceil(NN/256)

__global__ void count_deg_k(const int* __restrict__ dst, int* __restrict__ deg) {
    int t = blockIdx.x * 256 + threadIdx.x;
    if (t < EE) atomicAdd(&deg[dst[t]], 1);
}

__global__ void inv_deg_k(const int* __restrict__ deg, float* __restrict__ invd) {
    int t = blockIdx.x * 256 + threadIdx.x;
    if (t < NN) invd[t] = 1.0f / fmaxf((float)deg[t], 1.0f);
}

// ---- exclusive scan of deg -> row_ptr (3 kernels) ----
__global__ void scan1_k(const int* __restrict__ deg, int* __restrict__ row_ptr,
                        int* __restrict__ bsum) {
    __shared__ int s[256];
    int tid = threadIdx.x;
    int i = blockIdx.x * 256 + tid;
    int v = (i < NN) ? deg[i] : 0;
    s[tid] = v;
    __syncthreads();
    #pragma unroll
    for (int off = 1; off < 256; off <<= 1) {
        int t = (tid >= off) ? s[tid - off] : 0;
        __syncthreads();
        s[tid] += t;
        __syncthreads();
    }
    if (i < NN) row_ptr[i] = s[tid] - v;   // exclusive
    if (tid == 255) bsum[blockIdx.x] = s[255];
}

__global__ void scan2_k(const int* __restrict__ bsum, int* __restrict__ boff) {
    __shared__ int s[512];
    int tid = threadIdx.x;
    int v = (tid < NB_SCAN) ? bsum[tid] : 0;
    s[tid] = v;
    __syncthreads();
    #pragma unroll
    for (int off = 1; off < 512; off <<= 1) {
        int t = (tid >= off) ? s[tid - off] : 0;
        __syncthreads();
        s[tid] += t;
        __syncthreads();
    }
    if (tid < NB_SCAN) boff[tid] = s[tid] - v;   // exclusive
}

__global__ void scan3_k(int* __restrict__ row_ptr, const int* __restrict__ boff,
                        int* __restrict__ cursor) {
    int i = blockIdx.x * 256 + threadIdx.x;
    if (i < NN) {
        int r = row_ptr[i] + boff[blockIdx.x];
        row_ptr[i] = r;
        cursor[i] = r;
    }
    if (i == 0) row_ptr[NN] = EE;
}

__global__ void fill_csr_k(const int* __restrict__ src, const int* __restrict__ dst,
                           int* __restrict__ cursor, int* __restrict__ csr) {
    int e = blockIdx.x * 256 + threadIdx.x;
    if (e < EE) {
        int pos = atomicAdd(&cursor[dst[e]], 1);
        csr[pos] = src[e];
    }
}

// mean aggregation by gather: half-wave (32 lanes, float4 each) per node.
__global__ void gather_k(const float4* __restrict__ feat, const int* __restrict__ csr,
                         const int* __restrict__ row_ptr, const float* __restrict__ invd,
                         float4* __restrict__ agg) {
    int t = blockIdx.x * 256 + threadIdx.x;
    int node = t >> 5;
    int lane = t & 31;
    if (node >= NN) return;
    int e = row_ptr[node];
    int e1 = row_ptr[node + 1];
    float4 a0 = make_float4(0.f, 0.f, 0.f, 0.f);
    float4 a1 = make_float4(0.f, 0.f, 0.f, 0.f);
    for (; e + 1 < e1; e += 2) {
        int sa = csr[e], sb = csr[e + 1];
        float4 va = feat[(long long)sa * 32 + lane];
        float4 vb = feat[(long long)sb * 32 + lane];
        a0.x += va.x; a0.y += va.y; a0.z += va.z; a0.w += va.w;
        a1.x += vb.x; a1.y += vb.y; a1.z += vb.z; a1.w += vb.w;
    }
    if (e < e1) {
        int sa = csr[e];
        float4 va = feat[(long long)sa * 32 + lane];
        a0.x += va.x; a0.y += va.y; a0.z += va.z; a0.w += va.w;
    }
    float inv = invd[node];
    a0.x = (a0.x + a1.x) * inv;
    a0.y = (a0.y + a1.y) * inv;
    a0.z = (a0.z + a1.z) * inv;
    a0.w = (a0.w + a1.w) * inv;
    agg[(long long)node * 32 + lane] = a0;
}

// h_out = act( [mean | h_in] @ [Wl ; Wr] + b ), K fixed at 128+128=256.
// Block: 64 rows x OUTD cols, 256 threads, each 4 rows x (OUTD/16) cols.
// agg already holds the MEAN (pre-scaled by invd in gather_k).
template<int OUTD, bool RELU>
__global__ __launch_bounds__(256) void gemm_sage_k(
    const float* __restrict__ agg,
    const float* __restrict__ hin, const float* __restrict__ Wl,
    const float* __restrict__ bl, const float* __restrict__ Wr,
    float* __restrict__ hout)
{
    constexpr int CPT = OUTD / 16;
    constexpr int F4  = OUTD / 4;
    __shared__ float As[16][64];
    __shared__ float Ws[16][OUTD];

    const int tid = threadIdx.x;
    const int tx = tid & 15, ty = tid >> 4;
    const int row0 = blockIdx.x * 64;

    float acc[4][CPT];
    #pragma unroll
    for (int i = 0; i < 4; ++i)
        #pragma unroll
        for (int j = 0; j < CPT; ++j) acc[i][j] = 0.f;

    const int lr = tid >> 2;
    const int lq = tid & 3;
    const int grow = row0 + lr;
    const bool rvalid = grow < NN;

    for (int kc = 0; kc < 16; ++kc) {
        float4 av = make_float4(0.f, 0.f, 0.f, 0.f);
        if (rvalid) {
            if (kc < 8) {
                av = ((const float4*)agg)[(long long)grow * 32 + kc * 4 + lq];
            } else {
                av = ((const float4*)hin)[(long long)grow * 32 + (kc - 8) * 4 + lq];
            }
        }
        As[lq * 4 + 0][lr] = av.x;
        As[lq * 4 + 1][lr] = av.y;
        As[lq * 4 + 2][lr] = av.z;
        As[lq * 4 + 3][lr] = av.w;

        #pragma unroll
        for (int m = 0; m < OUTD / 64; ++m) {
            int idx = tid + m * 256;
            int kk = idx / F4, f4 = idx % F4;
            int kg = kc * 16 + kk;
            float4 wv = (kg < 128) ? ((const float4*)Wl)[(long long)kg * F4 + f4]
                                   : ((const float4*)Wr)[(long long)(kg - 128) * F4 + f4];
            ((float4*)&Ws[kk][0])[f4] = wv;
        }
        __syncthreads();

        #pragma unroll
        for (int kk = 0; kk < 16; ++kk) {
            float a0 = As[kk][ty];
            float a1 = As[kk][ty + 16];
            float a2 = As[kk][ty + 32];
            float a3 = As[kk][ty + 48];
            float w[CPT];
            #pragma unroll
            for (int j4 = 0; j4 < CPT / 4; ++j4) {
                float4 wv = ((const float4*)&Ws[kk][0])[tx * (CPT / 4) + j4];
                w[j4 * 4 + 0] = wv.x; w[j4 * 4 + 1] = wv.y;
                w[j4 * 4 + 2] = wv.z; w[j4 * 4 + 3] = wv.w;
            }
            #pragma unroll
            for (int j = 0; j < CPT; ++j) {
                acc[0][j] += a0 * w[j];
                acc[1][j] += a1 * w[j];
                acc[2][j] += a2 * w[j];
                acc[3][j] += a3 * w[j];
            }
        }
        __syncthreads();
    }

    #pragma unroll
    for (int i = 0; i < 4; ++i) {
        int r = row0 + ty + 16 * i;
        if (r < NN) {
            #pragma unroll
            for (int j4 = 0; j4 < CPT / 4; ++j4) {
                int c = tx * CPT + j4 * 4;
                float4 o;
                o.x = acc[i][j4 * 4 + 0] + bl[c + 0];
                o.y = acc[i][j4 * 4 + 1] + bl[c + 1];
                o.z = acc[i][j4 * 4 + 2] + bl[c + 2];
                o.w = acc[i][j4 * 4 + 3] + bl[c + 3];
                if (RELU) {
                    o.x = fmaxf(o.x, 0.f); o.y = fmaxf(o.y, 0.f);
                    o.z = fmaxf(o.z, 0.f); o.w = fmaxf(o.w, 0.f);
                }
                ((float4*)hout)[((long long)r * OUTD + c) >> 2] = o;
            }
        }
    }
}

// 16 lanes per scored edge; float4 per lane covers 64 dims.
__global__ void score_k(const float4* __restrict__ h2, const int* __restrict__ pos,
                        const int* __restrict__ neg, float* __restrict__ out) {
    int t = blockIdx.x * 256 + threadIdx.x;
    int eg = t >> 4, l = t & 15;
    if (eg >= 2 * EPE) return;
    int a, b;
    if (eg < EPE) { a = pos[eg]; b = pos[EPE + eg]; }
    else { int e2 = eg - EPE; a = neg[e2]; b = neg[EPE + e2]; }
    float4 va = h2[(long long)a * 16 + l];
    float4 vb = h2[(long long)b * 16 + l];
    float p = va.x * vb.x + va.y * vb.y + va.z * vb.z + va.w * vb.w;
    p += __shfl_xor(p, 1, 16);
    p += __shfl_xor(p, 2, 16);
    p += __shfl_xor(p, 4, 16);
    p += __shfl_xor(p, 8, 16);
    if (l == 0) out[eg] = p;
}

extern "C" void kernel_launch(void* const* d_in, const int* in_sizes, int n_in,
                              void* d_out, int out_size, void* d_ws, size_t ws_size,
                              hipStream_t stream) {
    const float* x   = (const float*)d_in[0];
    const int*   ei  = (const int*)d_in[1];
    const int*   pei = (const int*)d_in[2];
    const int*   nei = (const int*)d_in[3];
    const float* Wl0 = (const float*)d_in[4];
    const float* bl0 = (const float*)d_in[5];
    const float* Wr0 = (const float*)d_in[6];
    const float* Wl1 = (const float*)d_in[7];
    const float* bl1 = (const float*)d_in[8];
    const float* Wr1 = (const float*)d_in[9];
    float* out = (float*)d_out;

    char* ws = (char*)d_ws;
    size_t off = 0;
    auto alloc = [&](size_t bytes) {
        void* p = ws + off;
        off = (off + bytes + 255) & ~(size_t)255;
        return p;
    };
    int*   deg     = (int*)  alloc((size_t)NN * 4);
    float* invd    = (float*)alloc((size_t)NN * 4);
    int*   row_ptr = (int*)  alloc((size_t)(NN + 1) * 4);
    int*   cursor  = (int*)  alloc((size_t)NN * 4);
    int*   bsum    = (int*)  alloc((size_t)NB_SCAN * 4);
    int*   boff    = (int*)  alloc((size_t)NB_SCAN * 4);
    float* agg     = (float*)alloc((size_t)NN * 128 * 4);
    float* h1      = (float*)alloc((size_t)NN * 128 * 4);
    float* h2      = (float*)alloc((size_t)NN * 64 * 4);
    int*   csr     = (int*)h2;   // alias: csr dead before h2 is written

    const int* src = ei;        // edge_index[0]
    const int* dst = ei + EE;   // edge_index[1]

    hipMemsetAsync(deg, 0, (size_t)NN * 4, stream);

    // CSR build
    count_deg_k<<<(EE + 255) / 256, 256, 0, stream>>>(dst, deg);
    inv_deg_k<<<(NN + 255) / 256, 256, 0, stream>>>(deg, invd);
    scan1_k<<<NB_SCAN, 256, 0, stream>>>(deg, row_ptr, bsum);
    scan2_k<<<1, 512, 0, stream>>>(bsum, boff);
    scan3_k<<<NB_SCAN, 256, 0, stream>>>(row_ptr, boff, cursor);
    fill_csr_k<<<(EE + 255) / 256, 256, 0, stream>>>(src, dst, cursor, csr);

    // layer 0
    gather_k<<<(NN * 32 + 255) / 256, 256, 0, stream>>>((const float4*)x, csr, row_ptr, invd, (float4*)agg);
    gemm_sage_k<128, true><<<(NN + 63) / 64, 256, 0, stream>>>(agg, x, Wl0, bl0, Wr0, h1);

    // layer 1
    gather_k<<<(NN * 32 + 255) / 256, 256, 0, stream>>>((const float4*)h1, csr, row_ptr, invd, (float4*)agg);
    gemm_sage_k<64, false><<<(NN + 63) / 64, 256, 0, stream>>>(agg, h1, Wl1, bl1, Wr1, h2);

    // scoring
    score_k<<<(2 * EPE * 16 + 255) / 256, 256, 0, stream>>>((const float4*)h2, pei, nei, out);
}

// Round 3
// 489.424 us; speedup vs baseline: 11.8063x; 1.5326x over previous
//
#include <hip/hip_runtime.h>

#define NN 100000
#define EE 1600000
#define EPE 500000
#define NB_SCAN 391   // ceil(NN/256)

typedef short bf8_t __attribute__((ext_vector_type(8)));   // 8 x bf16 (4 VGPRs)
typedef float f4_t  __attribute__((ext_vector_type(4)));   // MFMA accumulator

__device__ __forceinline__ unsigned short f2bf(float f) {
    unsigned u = __float_as_uint(f);
    unsigned r = (u + 0x7fffu + ((u >> 16) & 1u)) >> 16;   // RNE
    return (unsigned short)r;
}
__device__ __forceinline__ float bfl(unsigned u) { return __uint_as_float(u << 16); }
__device__ __forceinline__ float bfh(unsigned u) { return __uint_as_float(u & 0xffff0000u); }

// ---------------- CSR build ----------------
__global__ void count_deg_k(const int* __restrict__ dst, int* __restrict__ deg) {
    int t = blockIdx.x * 256 + threadIdx.x;
    if (t < EE) atomicAdd(&deg[dst[t]], 1);
}

__global__ void inv_deg_k(const int* __restrict__ deg, float* __restrict__ invd) {
    int t = blockIdx.x * 256 + threadIdx.x;
    if (t < NN) invd[t] = 1.0f / fmaxf((float)deg[t], 1.0f);
}

__global__ void scan1_k(const int* __restrict__ deg, int* __restrict__ row_ptr,
                        int* __restrict__ bsum) {
    __shared__ int s[256];
    int tid = threadIdx.x;
    int i = blockIdx.x * 256 + tid;
    int v = (i < NN) ? deg[i] : 0;
    s[tid] = v;
    __syncthreads();
    #pragma unroll
    for (int off = 1; off < 256; off <<= 1) {
        int t = (tid >= off) ? s[tid - off] : 0;
        __syncthreads();
        s[tid] += t;
        __syncthreads();
    }
    if (i < NN) row_ptr[i] = s[tid] - v;
    if (tid == 255) bsum[blockIdx.x] = s[255];
}

__global__ void scan2_k(const int* __restrict__ bsum, int* __restrict__ boff) {
    __shared__ int s[512];
    int tid = threadIdx.x;
    int v = (tid < NB_SCAN) ? bsum[tid] : 0;
    s[tid] = v;
    __syncthreads();
    #pragma unroll
    for (int off = 1; off < 512; off <<= 1) {
        int t = (tid >= off) ? s[tid - off] : 0;
        __syncthreads();
        s[tid] += t;
        __syncthreads();
    }
    if (tid < NB_SCAN) boff[tid] = s[tid] - v;
}

__global__ void scan3_k(int* __restrict__ row_ptr, const int* __restrict__ boff,
                        int* __restrict__ cursor) {
    int i = blockIdx.x * 256 + threadIdx.x;
    if (i < NN) {
        int r = row_ptr[i] + boff[blockIdx.x];
        row_ptr[i] = r;
        cursor[i] = r;
    }
    if (i == 0) row_ptr[NN] = EE;
}

__global__ void fill_csr_k(const int* __restrict__ src, const int* __restrict__ dst,
                           int* __restrict__ cursor, int* __restrict__ csr) {
    int e = blockIdx.x * 256 + threadIdx.x;
    if (e < EE) {
        int pos = atomicAdd(&cursor[dst[e]], 1);
        csr[pos] = src[e];
    }
}

// ---------------- weight pack into B-fragment order ----------------
// Bp[kt][n][q][j] = concat(Wl,Wr)[kt*32 + q*8 + j][n], bf16.
// One thread per (kt,n,q) -> 8 ushorts (16 B).
__global__ void pack_b_k(const float* __restrict__ Wl, const float* __restrict__ Wr,
                         int ncl, int ntot, unsigned short* __restrict__ Bp) {
    int t = blockIdx.x * 256 + threadIdx.x;
    if (t >= 4 * ntot * 4) return;
    int q = t & 3;
    int n = (t >> 2) % ntot;
    int kt = t / (4 * ntot);
    int ncr = ntot - ncl;
    unsigned short o[8];
    #pragma unroll
    for (int j = 0; j < 8; ++j) {
        int k = kt * 32 + q * 8 + j;
        float v = (n < ncl) ? Wl[(size_t)k * ncl + n] : Wr[(size_t)k * ncr + (n - ncl)];
        o[j] = f2bf(v);
    }
    uint4 w;
    w.x = (unsigned)o[0] | ((unsigned)o[1] << 16);
    w.y = (unsigned)o[2] | ((unsigned)o[3] << 16);
    w.z = (unsigned)o[4] | ((unsigned)o[5] << 16);
    w.w = (unsigned)o[6] | ((unsigned)o[7] << 16);
    *(uint4*)(Bp + (size_t)t * 8) = w;
}

// ---------------- MFMA GEMM: [t | r] = A @ [Wl | Wr], K=128 ----------------
// Per wave: 16 rows x NCOLS cols. A-frag: m=lane&15, k=q*8+j. D: col=lane&15, row=q*4+reg.
template<int NCOLS, int TCOLS, bool AFP32>
__global__ __launch_bounds__(256) void gemm_k(
    const void* __restrict__ Av, const unsigned short* __restrict__ Bp,
    unsigned short* __restrict__ Tout, unsigned short* __restrict__ Rout)
{
    constexpr int NT = NCOLS / 16;
    int wave = threadIdx.x >> 6;
    int lane = threadIdx.x & 63;
    int ln = lane & 15, q = lane >> 4;
    int row0 = (blockIdx.x * 4 + wave) * 16;
    if (row0 >= NN) return;
    int arow = row0 + ln;

    f4_t acc[NT];
    #pragma unroll
    for (int nt = 0; nt < NT; ++nt) acc[nt] = (f4_t){0.f, 0.f, 0.f, 0.f};

    #pragma unroll
    for (int kt = 0; kt < 4; ++kt) {
        bf8_t a;
        if (AFP32) {
            const float* ap = (const float*)Av + (size_t)arow * 128 + kt * 32 + q * 8;
            f4_t a0 = *(const f4_t*)ap;
            f4_t a1 = *(const f4_t*)(ap + 4);
            #pragma unroll
            for (int j = 0; j < 4; ++j) {
                a[j]     = (short)f2bf(a0[j]);
                a[4 + j] = (short)f2bf(a1[j]);
            }
        } else {
            a = *(const bf8_t*)((const unsigned short*)Av + (size_t)arow * 128 + kt * 32 + q * 8);
        }
        const unsigned short* bb = Bp + (size_t)kt * NCOLS * 32 + (size_t)ln * 32 + q * 8;
        #pragma unroll
        for (int nt = 0; nt < NT; ++nt) {
            bf8_t b = *(const bf8_t*)(bb + nt * 512);
            acc[nt] = __builtin_amdgcn_mfma_f32_16x16x32_bf16(a, b, acc[nt], 0, 0, 0);
        }
    }

    #pragma unroll
    for (int nt = 0; nt < NT; ++nt) {
        #pragma unroll
        for (int r = 0; r < 4; ++r) {
            int row = row0 + q * 4 + r;
            int col = nt * 16 + ln;
            unsigned short v = f2bf(acc[nt][r]);
            if (col < TCOLS) Tout[(size_t)row * TCOLS + col] = v;
            else             Rout[(size_t)row * (NCOLS - TCOLS) + (col - TCOLS)] = v;
        }
    }
}

// ---------------- fused gather-mean + combine ----------------
// h[node] = act( invd*sum_{nbr} t[nbr] + r[node] + bias )  -> bf16
// LPN = 2^LPNS lanes per node, 8 bf16 (16 B) per lane. WIDTH = LPN*8.
template<int LPNS, int WIDTH, bool RELU>
__global__ void gather_fuse_k(const unsigned short* __restrict__ feat,
                              const int* __restrict__ csr, const int* __restrict__ row_ptr,
                              const float* __restrict__ invd,
                              const unsigned short* __restrict__ rterm,
                              const float* __restrict__ bias,
                              unsigned short* __restrict__ hout)
{
    int t = blockIdx.x * 256 + threadIdx.x;
    int node = t >> LPNS;
    int lane = t & ((1 << LPNS) - 1);
    if (node >= NN) return;
    int e = row_ptr[node];
    int e1 = row_ptr[node + 1];

    float a0[8] = {0.f, 0.f, 0.f, 0.f, 0.f, 0.f, 0.f, 0.f};
    float a1[8] = {0.f, 0.f, 0.f, 0.f, 0.f, 0.f, 0.f, 0.f};
    for (; e + 1 < e1; e += 2) {
        int s0 = csr[e], s1 = csr[e + 1];
        uint4 v0 = *(const uint4*)(feat + (size_t)s0 * WIDTH + lane * 8);
        uint4 v1 = *(const uint4*)(feat + (size_t)s1 * WIDTH + lane * 8);
        a0[0] += bfl(v0.x); a0[1] += bfh(v0.x); a0[2] += bfl(v0.y); a0[3] += bfh(v0.y);
        a0[4] += bfl(v0.z); a0[5] += bfh(v0.z); a0[6] += bfl(v0.w); a0[7] += bfh(v0.w);
        a1[0] += bfl(v1.x); a1[1] += bfh(v1.x); a1[2] += bfl(v1.y); a1[3] += bfh(v1.y);
        a1[4] += bfl(v1.z); a1[5] += bfh(v1.z); a1[6] += bfl(v1.w); a1[7] += bfh(v1.w);
    }
    if (e < e1) {
        int s0 = csr[e];
        uint4 v0 = *(const uint4*)(feat + (size_t)s0 * WIDTH + lane * 8);
        a0[0] += bfl(v0.x); a0[1] += bfh(v0.x); a0[2] += bfl(v0.y); a0[3] += bfh(v0.y);
        a0[4] += bfl(v0.z); a0[5] += bfh(v0.z); a0[6] += bfl(v0.w); a0[7] += bfh(v0.w);
    }
    float inv = invd[node];
    uint4 rv = *(const uint4*)(rterm + (size_t)node * WIDTH + lane * 8);
    float rr[8] = {bfl(rv.x), bfh(rv.x), bfl(rv.y), bfh(rv.y),
                   bfl(rv.z), bfh(rv.z), bfl(rv.w), bfh(rv.w)};
    f4_t b0 = *(const f4_t*)(bias + lane * 8);
    f4_t b1 = *(const f4_t*)(bias + lane * 8 + 4);
    float o[8];
    #pragma unroll
    for (int j = 0; j < 8; ++j) {
        float bj = (j < 4) ? b0[j] : b1[j - 4];
        float v = (a0[j] + a1[j]) * inv + rr[j] + bj;
        o[j] = RELU ? fmaxf(v, 0.f) : v;
    }
    uint4 w;
    w.x = (unsigned)f2bf(o[0]) | ((unsigned)f2bf(o[1]) << 16);
    w.y = (unsigned)f2bf(o[2]) | ((unsigned)f2bf(o[3]) << 16);
    w.z = (unsigned)f2bf(o[4]) | ((unsigned)f2bf(o[5]) << 16);
    w.w = (unsigned)f2bf(o[6]) | ((unsigned)f2bf(o[7]) << 16);
    *(uint4*)(hout + (size_t)node * WIDTH + lane * 8) = w;
}

// ---------------- edge scoring: 8 lanes x 8 bf16 per edge ----------------
__global__ void score_k(const unsigned short* __restrict__ h2b, const int* __restrict__ pos,
                        const int* __restrict__ neg, float* __restrict__ out) {
    int t = blockIdx.x * 256 + threadIdx.x;
    int eg = t >> 3, l = t & 7;
    if (eg >= 2 * EPE) return;
    int a, b;
    if (eg < EPE) { a = pos[eg]; b = pos[EPE + eg]; }
    else { int e2 = eg - EPE; a = neg[e2]; b = neg[EPE + e2]; }
    uint4 va = *(const uint4*)(h2b + (size_t)a * 64 + l * 8);
    uint4 vb = *(const uint4*)(h2b + (size_t)b * 64 + l * 8);
    float p = bfl(va.x) * bfl(vb.x) + bfh(va.x) * bfh(vb.x)
            + bfl(va.y) * bfl(vb.y) + bfh(va.y) * bfh(vb.y)
            + bfl(va.z) * bfl(vb.z) + bfh(va.z) * bfh(vb.z)
            + bfl(va.w) * bfl(vb.w) + bfh(va.w) * bfh(vb.w);
    p += __shfl_xor(p, 1, 8);
    p += __shfl_xor(p, 2, 8);
    p += __shfl_xor(p, 4, 8);
    if (l == 0) out[eg] = p;
}

extern "C" void kernel_launch(void* const* d_in, const int* in_sizes, int n_in,
                              void* d_out, int out_size, void* d_ws, size_t ws_size,
                              hipStream_t stream) {
    const float* x   = (const float*)d_in[0];
    const int*   ei  = (const int*)d_in[1];
    const int*   pei = (const int*)d_in[2];
    const int*   nei = (const int*)d_in[3];
    const float* Wl0 = (const float*)d_in[4];
    const float* bl0 = (const float*)d_in[5];
    const float* Wr0 = (const float*)d_in[6];
    const float* Wl1 = (const float*)d_in[7];
    const float* bl1 = (const float*)d_in[8];
    const float* Wr1 = (const float*)d_in[9];
    float* out = (float*)d_out;

    char* ws = (char*)d_ws;
    size_t off = 0;
    auto alloc = [&](size_t bytes) {
        void* p = ws + off;
        off = (off + bytes + 255) & ~(size_t)255;
        return p;
    };
    int*   deg     = (int*)  alloc((size_t)NN * 4);
    float* invd    = (float*)alloc((size_t)NN * 4);
    int*   row_ptr = (int*)  alloc((size_t)(NN + 1) * 4);
    int*   cursor  = (int*)  alloc((size_t)NN * 4);
    int*   bsum    = (int*)  alloc((size_t)NB_SCAN * 4);
    int*   boff    = (int*)  alloc((size_t)NB_SCAN * 4);
    int*   csr     = (int*)  alloc((size_t)EE * 4);
    unsigned short* Bp0 = (unsigned short*)alloc((size_t)4 * 256 * 4 * 8 * 2);
    unsigned short* Bp1 = (unsigned short*)alloc((size_t)4 * 128 * 4 * 8 * 2);
    unsigned short* t0  = (unsigned short*)alloc((size_t)NN * 128 * 2);  // reused as t1
    unsigned short* r0b = (unsigned short*)alloc((size_t)NN * 128 * 2);  // reused as r1b
    unsigned short* h1b = (unsigned short*)alloc((size_t)NN * 128 * 2);  // reused as h2b
    unsigned short* t1  = t0;
    unsigned short* r1b = r0b;
    unsigned short* h2b = h1b;

    const int* src = ei;        // edge_index[0]
    const int* dst = ei + EE;   // edge_index[1]

    hipMemsetAsync(deg, 0, (size_t)NN * 4, stream);

    // CSR build
    count_deg_k<<<(EE + 255) / 256, 256, 0, stream>>>(dst, deg);
    inv_deg_k<<<(NN + 255) / 256, 256, 0, stream>>>(deg, invd);
    scan1_k<<<NB_SCAN, 256, 0, stream>>>(deg, row_ptr, bsum);
    scan2_k<<<1, 512, 0, stream>>>(bsum, boff);
    scan3_k<<<NB_SCAN, 256, 0, stream>>>(row_ptr, boff, cursor);
    fill_csr_k<<<(EE + 255) / 256, 256, 0, stream>>>(src, dst, cursor, csr);

    // weight packing
    pack_b_k<<<16, 256, 0, stream>>>(Wl0, Wr0, 128, 256, Bp0);
    pack_b_k<<<8, 256, 0, stream>>>(Wl1, Wr1, 64, 128, Bp1);

    // layer 0: [t0 | r0] = x @ [Wl0 | Wr0]; h1 = relu(mean(t0) + r0 + b0)
    gemm_k<256, 128, true><<<1563, 256, 0, stream>>>(x, Bp0, t0, r0b);
    gather_fuse_k<4, 128, true><<<(NN * 16) / 256, 256, 0, stream>>>(
        t0, csr, row_ptr, invd, r0b, bl0, h1b);

    // layer 1: [t1 | r1] = h1 @ [Wl1 | Wr1]; h2 = mean(t1) + r1 + b1
    gemm_k<128, 64, false><<<1563, 256, 0, stream>>>(h1b, Bp1, t1, r1b);
    gather_fuse_k<3, 64, false><<<(NN * 8) / 256, 256, 0, stream>>>(
        t1, csr, row_ptr, invd, r1b, bl1, h2b);

    // scoring
    score_k<<<(2 * EPE * 8) / 256, 256, 0, stream>>>(h2b, pei, nei, out);
}

// Round 4
// 345.271 us; speedup vs baseline: 16.7356x; 1.4175x over previous
//
#include <hip/hip_runtime.h>

#define NN 100000
#define EE 1600000
#define EPE 500000
#define NBINS 196        // ceil(NN/512), bin = dst >> 9
#define BCAP 12288       // slots per bin (avg 8192, sigma ~90 -> huge margin)
#define EPB 4096         // edges per block in binpass1
#define NB1 391          // ceil(EE/EPB)

typedef short bf8_t __attribute__((ext_vector_type(8)));   // 8 x bf16 (4 VGPRs)
typedef float f4_t  __attribute__((ext_vector_type(4)));   // MFMA accumulator

__device__ __forceinline__ unsigned short f2bf(float f) {
    unsigned u = __float_as_uint(f);
    unsigned r = (u + 0x7fffu + ((u >> 16) & 1u)) >> 16;   // RNE
    return (unsigned short)r;
}
__device__ __forceinline__ float bfl(unsigned u) { return __uint_as_float(u << 16); }
__device__ __forceinline__ float bfh(unsigned u) { return __uint_as_float(u & 0xffff0000u); }

// ---------------- binned CSR build ----------------
// pass 1: bucket edges by dst>>9 into per-bin append buffers (L2-hot regions).
__global__ __launch_bounds__(256) void binpass1_k(
    const int* __restrict__ src, const int* __restrict__ dst,
    int* __restrict__ bin_cnt, int* __restrict__ binbuf)
{
    __shared__ int cnt_l[NBINS];
    __shared__ int base_l[NBINS];
    int tid = threadIdx.x;
    int e0 = blockIdx.x * EPB;
    for (int i = tid; i < NBINS; i += 256) cnt_l[i] = 0;
    __syncthreads();

    int pk[16];
    #pragma unroll
    for (int i = 0; i < 16; ++i) {
        int e = e0 + tid + i * 256;
        pk[i] = -1;
        if (e < EE) {
            int b = dst[e] >> 9;
            int r = atomicAdd(&cnt_l[b], 1);        // r < 4096
            pk[i] = (b << 16) | r;
        }
    }
    __syncthreads();
    for (int i = tid; i < NBINS; i += 256)
        base_l[i] = atomicAdd(&bin_cnt[i], cnt_l[i]);
    __syncthreads();

    #pragma unroll
    for (int i = 0; i < 16; ++i) {
        int e = e0 + tid + i * 256;
        if (e >= EE) continue;
        int b = pk[i] >> 16, r = pk[i] & 0xFFFF;
        int d = dst[e], s = src[e];
        binbuf[b * BCAP + base_l[b] + r] = ((d & 511) << 17) | s;  // src<2^17
    }
}

// exclusive scan over NBINS bin counts
__global__ void binscan_k(const int* __restrict__ bin_cnt, int* __restrict__ bin_base) {
    __shared__ int s[256];
    int tid = threadIdx.x;
    int v = (tid < NBINS) ? bin_cnt[tid] : 0;
    s[tid] = v;
    __syncthreads();
    #pragma unroll
    for (int off = 1; off < 256; off <<= 1) {
        int t = (tid >= off) ? s[tid - off] : 0;
        __syncthreads();
        s[tid] += t;
        __syncthreads();
    }
    if (tid < NBINS) bin_base[tid] = s[tid] - v;
}

// pass 2: one block per bin. Local degree count -> LDS scan -> row_ptr/invd,
// then place csr with LDS cursors. All scatter targets are L1/L2-hot.
__global__ __launch_bounds__(256) void binpass2_k(
    const int* __restrict__ binbuf, const int* __restrict__ bin_cnt,
    const int* __restrict__ bin_base, int* __restrict__ csr,
    int* __restrict__ row_ptr, float* __restrict__ invd)
{
    __shared__ int deg_l[512];
    __shared__ int off_l[512];
    __shared__ int cur_l[512];
    __shared__ int s[256];
    int tid = threadIdx.x;
    int b = blockIdx.x;
    int lo = b << 9;
    int n_here = min(512, NN - lo);
    int cnt = bin_cnt[b];
    int base = bin_base[b];
    const int* bb = binbuf + b * BCAP;

    deg_l[tid] = 0; deg_l[tid + 256] = 0;
    __syncthreads();
    for (int i = tid; i < cnt; i += 256)
        atomicAdd(&deg_l[bb[i] >> 17], 1);
    __syncthreads();

    // exclusive scan of deg_l[512] with 256 threads (pairwise)
    int a0 = deg_l[2 * tid], a1 = deg_l[2 * tid + 1];
    s[tid] = a0 + a1;
    __syncthreads();
    #pragma unroll
    for (int off = 1; off < 256; off <<= 1) {
        int t = (tid >= off) ? s[tid - off] : 0;
        __syncthreads();
        s[tid] += t;
        __syncthreads();
    }
    int excl = s[tid] - (a0 + a1);
    off_l[2 * tid] = excl;
    off_l[2 * tid + 1] = excl + a0;
    cur_l[2 * tid] = excl;
    cur_l[2 * tid + 1] = excl + a0;
    __syncthreads();

    for (int j = tid; j < n_here; j += 256) {
        row_ptr[lo + j] = base + off_l[j];
        invd[lo + j] = 1.0f / fmaxf((float)deg_l[j], 1.0f);
    }
    if (tid == 0 && b == NBINS - 1) row_ptr[NN] = EE;

    for (int i = tid; i < cnt; i += 256) {
        int v = bb[i];
        int dstl = v >> 17, srcv = v & 0x1FFFF;
        int pos = atomicAdd(&cur_l[dstl], 1);
        csr[base + pos] = srcv;
    }
}

// ---------------- weight pack into B-fragment order ----------------
__global__ void pack_b_k(const float* __restrict__ Wl, const float* __restrict__ Wr,
                         int ncl, int ntot, unsigned short* __restrict__ Bp) {
    int t = blockIdx.x * 256 + threadIdx.x;
    if (t >= 4 * ntot * 4) return;
    int q = t & 3;
    int n = (t >> 2) % ntot;
    int kt = t / (4 * ntot);
    int ncr = ntot - ncl;
    unsigned short o[8];
    #pragma unroll
    for (int j = 0; j < 8; ++j) {
        int k = kt * 32 + q * 8 + j;
        float v = (n < ncl) ? Wl[(size_t)k * ncl + n] : Wr[(size_t)k * ncr + (n - ncl)];
        o[j] = f2bf(v);
    }
    uint4 w;
    w.x = (unsigned)o[0] | ((unsigned)o[1] << 16);
    w.y = (unsigned)o[2] | ((unsigned)o[3] << 16);
    w.z = (unsigned)o[4] | ((unsigned)o[5] << 16);
    w.w = (unsigned)o[6] | ((unsigned)o[7] << 16);
    *(uint4*)(Bp + (size_t)t * 8) = w;
}

// ---------------- MFMA GEMM: [t | r] = A @ [Wl | Wr], K=128 ----------------
template<int NCOLS, int TCOLS, bool AFP32>
__global__ __launch_bounds__(256) void gemm_k(
    const void* __restrict__ Av, const unsigned short* __restrict__ Bp,
    unsigned short* __restrict__ Tout, unsigned short* __restrict__ Rout)
{
    constexpr int NT = NCOLS / 16;
    int wave = threadIdx.x >> 6;
    int lane = threadIdx.x & 63;
    int ln = lane & 15, q = lane >> 4;
    int row0 = (blockIdx.x * 4 + wave) * 16;
    if (row0 >= NN) return;
    int arow = row0 + ln;

    f4_t acc[NT];
    #pragma unroll
    for (int nt = 0; nt < NT; ++nt) acc[nt] = (f4_t){0.f, 0.f, 0.f, 0.f};

    #pragma unroll
    for (int kt = 0; kt < 4; ++kt) {
        bf8_t a;
        if (AFP32) {
            const float* ap = (const float*)Av + (size_t)arow * 128 + kt * 32 + q * 8;
            f4_t a0 = *(const f4_t*)ap;
            f4_t a1 = *(const f4_t*)(ap + 4);
            #pragma unroll
            for (int j = 0; j < 4; ++j) {
                a[j]     = (short)f2bf(a0[j]);
                a[4 + j] = (short)f2bf(a1[j]);
            }
        } else {
            a = *(const bf8_t*)((const unsigned short*)Av + (size_t)arow * 128 + kt * 32 + q * 8);
        }
        const unsigned short* bb = Bp + (size_t)kt * NCOLS * 32 + (size_t)ln * 32 + q * 8;
        #pragma unroll
        for (int nt = 0; nt < NT; ++nt) {
            bf8_t b = *(const bf8_t*)(bb + nt * 512);
            acc[nt] = __builtin_amdgcn_mfma_f32_16x16x32_bf16(a, b, acc[nt], 0, 0, 0);
        }
    }

    #pragma unroll
    for (int nt = 0; nt < NT; ++nt) {
        #pragma unroll
        for (int r = 0; r < 4; ++r) {
            int row = row0 + q * 4 + r;
            int col = nt * 16 + ln;
            unsigned short v = f2bf(acc[nt][r]);
            if (col < TCOLS) Tout[(size_t)row * TCOLS + col] = v;
            else             Rout[(size_t)row * (NCOLS - TCOLS) + (col - TCOLS)] = v;
        }
    }
}

// ---------------- fused gather-mean + combine ----------------
template<int LPNS, int WIDTH, bool RELU>
__global__ void gather_fuse_k(const unsigned short* __restrict__ feat,
                              const int* __restrict__ csr, const int* __restrict__ row_ptr,
                              const float* __restrict__ invd,
                              const unsigned short* __restrict__ rterm,
                              const float* __restrict__ bias,
                              unsigned short* __restrict__ hout)
{
    int t = blockIdx.x * 256 + threadIdx.x;
    int node = t >> LPNS;
    int lane = t & ((1 << LPNS) - 1);
    if (node >= NN) return;
    int e = row_ptr[node];
    int e1 = row_ptr[node + 1];

    float a0[8] = {0.f, 0.f, 0.f, 0.f, 0.f, 0.f, 0.f, 0.f};
    float a1[8] = {0.f, 0.f, 0.f, 0.f, 0.f, 0.f, 0.f, 0.f};
    for (; e + 1 < e1; e += 2) {
        int s0 = csr[e], s1 = csr[e + 1];
        uint4 v0 = *(const uint4*)(feat + (size_t)s0 * WIDTH + lane * 8);
        uint4 v1 = *(const uint4*)(feat + (size_t)s1 * WIDTH + lane * 8);
        a0[0] += bfl(v0.x); a0[1] += bfh(v0.x); a0[2] += bfl(v0.y); a0[3] += bfh(v0.y);
        a0[4] += bfl(v0.z); a0[5] += bfh(v0.z); a0[6] += bfl(v0.w); a0[7] += bfh(v0.w);
        a1[0] += bfl(v1.x); a1[1] += bfh(v1.x); a1[2] += bfl(v1.y); a1[3] += bfh(v1.y);
        a1[4] += bfl(v1.z); a1[5] += bfh(v1.z); a1[6] += bfl(v1.w); a1[7] += bfh(v1.w);
    }
    if (e < e1) {
        int s0 = csr[e];
        uint4 v0 = *(const uint4*)(feat + (size_t)s0 * WIDTH + lane * 8);
        a0[0] += bfl(v0.x); a0[1] += bfh(v0.x); a0[2] += bfl(v0.y); a0[3] += bfh(v0.y);
        a0[4] += bfl(v0.z); a0[5] += bfh(v0.z); a0[6] += bfl(v0.w); a0[7] += bfh(v0.w);
    }
    float inv = invd[node];
    uint4 rv = *(const uint4*)(rterm + (size_t)node * WIDTH + lane * 8);
    float rr[8] = {bfl(rv.x), bfh(rv.x), bfl(rv.y), bfh(rv.y),
                   bfl(rv.z), bfh(rv.z), bfl(rv.w), bfh(rv.w)};
    f4_t b0 = *(const f4_t*)(bias + lane * 8);
    f4_t b1 = *(const f4_t*)(bias + lane * 8 + 4);
    float o[8];
    #pragma unroll
    for (int j = 0; j < 8; ++j) {
        float bj = (j < 4) ? b0[j] : b1[j - 4];
        float v = (a0[j] + a1[j]) * inv + rr[j] + bj;
        o[j] = RELU ? fmaxf(v, 0.f) : v;
    }
    uint4 w;
    w.x = (unsigned)f2bf(o[0]) | ((unsigned)f2bf(o[1]) << 16);
    w.y = (unsigned)f2bf(o[2]) | ((unsigned)f2bf(o[3]) << 16);
    w.z = (unsigned)f2bf(o[4]) | ((unsigned)f2bf(o[5]) << 16);
    w.w = (unsigned)f2bf(o[6]) | ((unsigned)f2bf(o[7]) << 16);
    *(uint4*)(hout + (size_t)node * WIDTH + lane * 8) = w;
}

// ---------------- edge scoring: 8 lanes x 8 bf16 per edge ----------------
__global__ void score_k(const unsigned short* __restrict__ h2b, const int* __restrict__ pos,
                        const int* __restrict__ neg, float* __restrict__ out) {
    int t = blockIdx.x * 256 + threadIdx.x;
    int eg = t >> 3, l = t & 7;
    if (eg >= 2 * EPE) return;
    int a, b;
    if (eg < EPE) { a = pos[eg]; b = pos[EPE + eg]; }
    else { int e2 = eg - EPE; a = neg[e2]; b = neg[EPE + e2]; }
    uint4 va = *(const uint4*)(h2b + (size_t)a * 64 + l * 8);
    uint4 vb = *(const uint4*)(h2b + (size_t)b * 64 + l * 8);
    float p = bfl(va.x) * bfl(vb.x) + bfh(va.x) * bfh(vb.x)
            + bfl(va.y) * bfl(vb.y) + bfh(va.y) * bfh(vb.y)
            + bfl(va.z) * bfl(vb.z) + bfh(va.z) * bfh(vb.z)
            + bfl(va.w) * bfl(vb.w) + bfh(va.w) * bfh(vb.w);
    p += __shfl_xor(p, 1, 8);
    p += __shfl_xor(p, 2, 8);
    p += __shfl_xor(p, 4, 8);
    if (l == 0) out[eg] = p;
}

extern "C" void kernel_launch(void* const* d_in, const int* in_sizes, int n_in,
                              void* d_out, int out_size, void* d_ws, size_t ws_size,
                              hipStream_t stream) {
    const float* x   = (const float*)d_in[0];
    const int*   ei  = (const int*)d_in[1];
    const int*   pei = (const int*)d_in[2];
    const int*   nei = (const int*)d_in[3];
    const float* Wl0 = (const float*)d_in[4];
    const float* bl0 = (const float*)d_in[5];
    const float* Wr0 = (const float*)d_in[6];
    const float* Wl1 = (const float*)d_in[7];
    const float* bl1 = (const float*)d_in[8];
    const float* Wr1 = (const float*)d_in[9];
    float* out = (float*)d_out;

    char* ws = (char*)d_ws;
    size_t off = 0;
    auto alloc = [&](size_t bytes) {
        void* p = ws + off;
        off = (off + bytes + 255) & ~(size_t)255;
        return p;
    };
    float* invd     = (float*)alloc((size_t)NN * 4);
    int*   row_ptr  = (int*)  alloc((size_t)(NN + 1) * 4);
    int*   bin_cnt  = (int*)  alloc((size_t)NBINS * 4);
    int*   bin_base = (int*)  alloc((size_t)NBINS * 4);
    int*   binbuf   = (int*)  alloc((size_t)NBINS * BCAP * 4);
    int*   csr      = (int*)  alloc((size_t)EE * 4);
    unsigned short* Bp0 = (unsigned short*)alloc((size_t)4 * 256 * 4 * 8 * 2);
    unsigned short* Bp1 = (unsigned short*)alloc((size_t)4 * 128 * 4 * 8 * 2);
    unsigned short* t0  = (unsigned short*)alloc((size_t)NN * 128 * 2);  // reused as t1
    unsigned short* r0b = (unsigned short*)alloc((size_t)NN * 128 * 2);  // reused as r1b
    unsigned short* h1b = (unsigned short*)alloc((size_t)NN * 128 * 2);  // reused as h2b
    unsigned short* t1  = t0;
    unsigned short* r1b = r0b;
    unsigned short* h2b = h1b;

    const int* src = ei;        // edge_index[0]
    const int* dst = ei + EE;   // edge_index[1]

    hipMemsetAsync(bin_cnt, 0, (size_t)NBINS * 4, stream);

    // binned CSR build
    binpass1_k<<<NB1, 256, 0, stream>>>(src, dst, bin_cnt, binbuf);
    binscan_k<<<1, 256, 0, stream>>>(bin_cnt, bin_base);
    binpass2_k<<<NBINS, 256, 0, stream>>>(binbuf, bin_cnt, bin_base, csr, row_ptr, invd);

    // weight packing
    pack_b_k<<<16, 256, 0, stream>>>(Wl0, Wr0, 128, 256, Bp0);
    pack_b_k<<<8, 256, 0, stream>>>(Wl1, Wr1, 64, 128, Bp1);

    // layer 0: [t0 | r0] = x @ [Wl0 | Wr0]; h1 = relu(mean(t0) + r0 + b0)
    gemm_k<256, 128, true><<<1563, 256, 0, stream>>>(x, Bp0, t0, r0b);
    gather_fuse_k<4, 128, true><<<(NN * 16) / 256, 256, 0, stream>>>(
        t0, csr, row_ptr, invd, r0b, bl0, h1b);

    // layer 1: [t1 | r1] = h1 @ [Wl1 | Wr1]; h2 = mean(t1) + r1 + b1
    gemm_k<128, 64, false><<<1563, 256, 0, stream>>>(h1b, Bp1, t1, r1b);
    gather_fuse_k<3, 64, false><<<(NN * 8) / 256, 256, 0, stream>>>(
        t1, csr, row_ptr, invd, r1b, bl1, h2b);

    // scoring
    score_k<<<(2 * EPE * 8) / 256, 256, 0, stream>>>(h2b, pei, nei, out);
}

// Round 5
// 334.641 us; speedup vs baseline: 17.2671x; 1.0318x over previous
//
#include <hip/hip_runtime.h>

#define NN 100000
#define EE 1600000
#define EPE 500000
#define NBINS 196        // ceil(NN/512), bin = dst >> 9
#define BCAP 12288       // slots per bin (avg 8192, sigma ~90 -> huge margin)
#define EPB 2048         // edges per block in binpass1
#define NB1 782          // ceil(EE/EPB)

typedef short bf8_t __attribute__((ext_vector_type(8)));   // 8 x bf16 (4 VGPRs)
typedef float f4_t  __attribute__((ext_vector_type(4)));   // MFMA accumulator

__device__ __forceinline__ unsigned short f2bf(float f) {
    unsigned u = __float_as_uint(f);
    unsigned r = (u + 0x7fffu + ((u >> 16) & 1u)) >> 16;   // RNE
    return (unsigned short)r;
}
__device__ __forceinline__ float bfl(unsigned u) { return __uint_as_float(u << 16); }
__device__ __forceinline__ float bfh(unsigned u) { return __uint_as_float(u & 0xffff0000u); }

// ---------------- binned CSR build ----------------
// pass 1: bucket edges by dst>>9 into per-bin append buffers (L2-hot regions).
__global__ __launch_bounds__(256) void binpass1_k(
    const int* __restrict__ src, const int* __restrict__ dst,
    int* __restrict__ bin_cnt, int* __restrict__ binbuf)
{
    __shared__ int cnt_l[NBINS];
    __shared__ int base_l[NBINS];
    int tid = threadIdx.x;
    int e0 = blockIdx.x * EPB;
    for (int i = tid; i < NBINS; i += 256) cnt_l[i] = 0;
    __syncthreads();

    int pk[8];
    #pragma unroll
    for (int i = 0; i < 8; ++i) {
        int e = e0 + tid + i * 256;
        pk[i] = -1;
        if (e < EE) {
            int b = dst[e] >> 9;
            int r = atomicAdd(&cnt_l[b], 1);        // r < 2048
            pk[i] = (b << 16) | r;
        }
    }
    __syncthreads();
    for (int i = tid; i < NBINS; i += 256)
        base_l[i] = atomicAdd(&bin_cnt[i], cnt_l[i]);
    __syncthreads();

    #pragma unroll
    for (int i = 0; i < 8; ++i) {
        int e = e0 + tid + i * 256;
        if (e >= EE) continue;
        int b = pk[i] >> 16, r = pk[i] & 0xFFFF;
        int d = dst[e], s = src[e];
        binbuf[b * BCAP + base_l[b] + r] = ((d & 511) << 17) | s;  // src<2^17
    }
}

// pass 2: one block per bin. Scans ALL bin counts locally (replaces binscan),
// local degree count -> LDS scan -> row_ptr/invd, then place csr with LDS
// cursors. All scatter targets are L1/L2-hot.
__global__ __launch_bounds__(256) void binpass2_k(
    const int* __restrict__ binbuf, const int* __restrict__ bin_cnt,
    int* __restrict__ csr, int* __restrict__ row_ptr, float* __restrict__ invd)
{
    __shared__ int deg_l[512];
    __shared__ int off_l[512];
    __shared__ int cur_l[512];
    __shared__ int s[256];
    int tid = threadIdx.x;
    int b = blockIdx.x;
    int lo = b << 9;
    int n_here = min(512, NN - lo);

    // local scan of all bin counts -> base for this bin
    int bc = (tid < NBINS) ? bin_cnt[tid] : 0;
    s[tid] = bc;
    __syncthreads();
    #pragma unroll
    for (int off = 1; off < 256; off <<= 1) {
        int t = (tid >= off) ? s[tid - off] : 0;
        __syncthreads();
        s[tid] += t;
        __syncthreads();
    }
    int base = (b == 0) ? 0 : s[b - 1];
    int cnt = bin_cnt[b];
    const int* bb = binbuf + b * BCAP;
    __syncthreads();

    deg_l[tid] = 0; deg_l[tid + 256] = 0;
    __syncthreads();
    for (int i = tid; i < cnt; i += 256)
        atomicAdd(&deg_l[bb[i] >> 17], 1);
    __syncthreads();

    // exclusive scan of deg_l[512] with 256 threads (pairwise)
    int a0 = deg_l[2 * tid], a1 = deg_l[2 * tid + 1];
    s[tid] = a0 + a1;
    __syncthreads();
    #pragma unroll
    for (int off = 1; off < 256; off <<= 1) {
        int t = (tid >= off) ? s[tid - off] : 0;
        __syncthreads();
        s[tid] += t;
        __syncthreads();
    }
    int excl = s[tid] - (a0 + a1);
    off_l[2 * tid] = excl;
    off_l[2 * tid + 1] = excl + a0;
    cur_l[2 * tid] = excl;
    cur_l[2 * tid + 1] = excl + a0;
    __syncthreads();

    for (int j = tid; j < n_here; j += 256) {
        row_ptr[lo + j] = base + off_l[j];
        invd[lo + j] = 1.0f / fmaxf((float)deg_l[j], 1.0f);
    }
    if (tid == 0 && b == NBINS - 1) row_ptr[NN] = EE;

    for (int i = tid; i < cnt; i += 256) {
        int v = bb[i];
        int dstl = v >> 17, srcv = v & 0x1FFFF;
        int pos = atomicAdd(&cur_l[dstl], 1);
        csr[base + pos] = srcv;
    }
}

// ---------------- combined weight/bias pack ----------------
// Bp0: identity row order. Bp1: rows permuted to match h1's stored layout
// (stored offset m holds true col c(m) = ((m&7)<<4)|(m>>3), NTH=8).
// b0p[m] = bl0[c8(m)]; b1p[m] = bl1[c4(m)] with c4(m) = ((m&3)<<4)|(m>>2).
__global__ void pack_k(const float* __restrict__ Wl0, const float* __restrict__ Wr0,
                       const float* __restrict__ Wl1, const float* __restrict__ Wr1,
                       const float* __restrict__ bl0, const float* __restrict__ bl1,
                       unsigned short* __restrict__ Bp0, unsigned short* __restrict__ Bp1,
                       float* __restrict__ b0p, float* __restrict__ b1p)
{
    int t = blockIdx.x * 256 + threadIdx.x;
    if (t < 4096) {                     // Bp0: (kt, n, q), ntot=256, ncl=128
        int q = t & 3;
        int n = (t >> 2) & 255;
        int kt = t >> 10;
        unsigned short o[8];
        #pragma unroll
        for (int j = 0; j < 8; ++j) {
            int k = kt * 32 + q * 8 + j;
            float v = (n < 128) ? Wl0[(size_t)k * 128 + n] : Wr0[(size_t)k * 128 + (n - 128)];
            o[j] = f2bf(v);
        }
        uint4 w;
        w.x = (unsigned)o[0] | ((unsigned)o[1] << 16);
        w.y = (unsigned)o[2] | ((unsigned)o[3] << 16);
        w.z = (unsigned)o[4] | ((unsigned)o[5] << 16);
        w.w = (unsigned)o[6] | ((unsigned)o[7] << 16);
        *(uint4*)(Bp0 + (size_t)t * 8) = w;
    } else if (t < 6144) {              // Bp1: ntot=128, ncl=64, permuted rows
        int u = t - 4096;
        int q = u & 3;
        int n = (u >> 2) & 127;
        int kt = u >> 9;
        unsigned short o[8];
        #pragma unroll
        for (int j = 0; j < 8; ++j) {
            int k = kt * 32 + q * 8 + j;          // memory offset in h1 row
            int c = ((k & 7) << 4) | (k >> 3);    // true column
            float v = (n < 64) ? Wl1[(size_t)c * 64 + n] : Wr1[(size_t)c * 64 + (n - 64)];
            o[j] = f2bf(v);
        }
        uint4 w;
        w.x = (unsigned)o[0] | ((unsigned)o[1] << 16);
        w.y = (unsigned)o[2] | ((unsigned)o[3] << 16);
        w.z = (unsigned)o[4] | ((unsigned)o[5] << 16);
        w.w = (unsigned)o[6] | ((unsigned)o[7] << 16);
        *(uint4*)(Bp1 + (size_t)u * 8) = w;
    } else if (t < 6144 + 128) {
        int m = t - 6144;
        b0p[m] = bl0[((m & 7) << 4) | (m >> 3)];
    } else if (t < 6144 + 192) {
        int m = t - 6272;
        b1p[m] = bl1[((m & 3) << 4) | (m >> 2)];
    }
}

// ---------------- MFMA GEMM: [t | r] = A @ [Wl | Wr], K=128 ----------------
// Output rows stored in PERMUTED layout: offset m = ln*NTH + nt holds true
// col nt*16 + ln (per half). Downstream compensates (pack_k perm, score is
// permutation-invariant). Per lane: 8 wide coalesced stores.
template<int NCOLS, int TCOLS, bool AFP32>
__global__ __launch_bounds__(256) void gemm_k(
    const void* __restrict__ Av, const unsigned short* __restrict__ Bp,
    unsigned short* __restrict__ Tout, unsigned short* __restrict__ Rout)
{
    constexpr int NT = NCOLS / 16;
    constexpr int NTH = NCOLS / 32;   // accs per half (8 for layer0, 4 for layer1)
    int wave = threadIdx.x >> 6;
    int lane = threadIdx.x & 63;
    int ln = lane & 15, q = lane >> 4;
    int row0 = (blockIdx.x * 4 + wave) * 16;
    if (row0 >= NN) return;
    int arow = row0 + ln;

    f4_t acc[NT];
    #pragma unroll
    for (int nt = 0; nt < NT; ++nt) acc[nt] = (f4_t){0.f, 0.f, 0.f, 0.f};

    #pragma unroll
    for (int kt = 0; kt < 4; ++kt) {
        bf8_t a;
        if (AFP32) {
            const float* ap = (const float*)Av + (size_t)arow * 128 + kt * 32 + q * 8;
            f4_t a0 = *(const f4_t*)ap;
            f4_t a1 = *(const f4_t*)(ap + 4);
            #pragma unroll
            for (int j = 0; j < 4; ++j) {
                a[j]     = (short)f2bf(a0[j]);
                a[4 + j] = (short)f2bf(a1[j]);
            }
        } else {
            a = *(const bf8_t*)((const unsigned short*)Av + (size_t)arow * 128 + kt * 32 + q * 8);
        }
        const unsigned short* bb = Bp + (size_t)kt * NCOLS * 32 + (size_t)ln * 32 + q * 8;
        #pragma unroll
        for (int nt = 0; nt < NT; ++nt) {
            bf8_t b = *(const bf8_t*)(bb + nt * 512);
            acc[nt] = __builtin_amdgcn_mfma_f32_16x16x32_bf16(a, b, acc[nt], 0, 0, 0);
        }
    }

    #pragma unroll
    for (int r = 0; r < 4; ++r) {
        int row = row0 + q * 4 + r;
        if (NTH == 8) {
            uint4 wt, wr;
            wt.x = (unsigned)f2bf(acc[0][r]) | ((unsigned)f2bf(acc[1][r]) << 16);
            wt.y = (unsigned)f2bf(acc[2][r]) | ((unsigned)f2bf(acc[3][r]) << 16);
            wt.z = (unsigned)f2bf(acc[4][r]) | ((unsigned)f2bf(acc[5][r]) << 16);
            wt.w = (unsigned)f2bf(acc[6][r]) | ((unsigned)f2bf(acc[7][r]) << 16);
            wr.x = (unsigned)f2bf(acc[8][r])  | ((unsigned)f2bf(acc[9][r])  << 16);
            wr.y = (unsigned)f2bf(acc[10][r]) | ((unsigned)f2bf(acc[11][r]) << 16);
            wr.z = (unsigned)f2bf(acc[12][r]) | ((unsigned)f2bf(acc[13][r]) << 16);
            wr.w = (unsigned)f2bf(acc[14][r]) | ((unsigned)f2bf(acc[15][r]) << 16);
            *(uint4*)(Tout + (size_t)row * TCOLS + ln * 8) = wt;
            *(uint4*)(Rout + (size_t)row * TCOLS + ln * 8) = wr;
        } else {
            uint2 wt, wr;
            wt.x = (unsigned)f2bf(acc[0][r]) | ((unsigned)f2bf(acc[1][r]) << 16);
            wt.y = (unsigned)f2bf(acc[2][r]) | ((unsigned)f2bf(acc[3][r]) << 16);
            wr.x = (unsigned)f2bf(acc[4][r]) | ((unsigned)f2bf(acc[5][r]) << 16);
            wr.y = (unsigned)f2bf(acc[6][r]) | ((unsigned)f2bf(acc[7][r]) << 16);
            *(uint2*)(Tout + (size_t)row * TCOLS + ln * 4) = wt;
            *(uint2*)(Rout + (size_t)row * TCOLS + ln * 4) = wr;
        }
    }
}

// ---------------- fused gather-mean + combine ----------------
#define ACC8(a, v)                                                          \
    do {                                                                    \
        a[0] += bfl((v).x); a[1] += bfh((v).x);                             \
        a[2] += bfl((v).y); a[3] += bfh((v).y);                             \
        a[4] += bfl((v).z); a[5] += bfh((v).z);                             \
        a[6] += bfl((v).w); a[7] += bfh((v).w);                             \
    } while (0)

template<int LPNS, int WIDTH, bool RELU>
__global__ void gather_fuse_k(const unsigned short* __restrict__ feat,
                              const int* __restrict__ csr, const int* __restrict__ row_ptr,
                              const float* __restrict__ invd,
                              const unsigned short* __restrict__ rterm,
                              const float* __restrict__ bias,
                              unsigned short* __restrict__ hout)
{
    int t = blockIdx.x * 256 + threadIdx.x;
    int node = t >> LPNS;
    int lane = t & ((1 << LPNS) - 1);
    if (node >= NN) return;
    int e = row_ptr[node];
    int e1 = row_ptr[node + 1];
    const unsigned short* fb = feat + (size_t)lane * 8;

    float a0[8] = {0.f, 0.f, 0.f, 0.f, 0.f, 0.f, 0.f, 0.f};
    float a1[8] = {0.f, 0.f, 0.f, 0.f, 0.f, 0.f, 0.f, 0.f};
    for (; e + 3 < e1; e += 4) {
        int s0 = csr[e], s1 = csr[e + 1], s2 = csr[e + 2], s3 = csr[e + 3];
        uint4 v0 = *(const uint4*)(fb + (size_t)s0 * WIDTH);
        uint4 v1 = *(const uint4*)(fb + (size_t)s1 * WIDTH);
        uint4 v2 = *(const uint4*)(fb + (size_t)s2 * WIDTH);
        uint4 v3 = *(const uint4*)(fb + (size_t)s3 * WIDTH);
        ACC8(a0, v0); ACC8(a1, v1); ACC8(a0, v2); ACC8(a1, v3);
    }
    for (; e < e1; ++e) {
        int s0 = csr[e];
        uint4 v0 = *(const uint4*)(fb + (size_t)s0 * WIDTH);
        ACC8(a0, v0);
    }
    float inv = invd[node];
    uint4 rv = *(const uint4*)(rterm + (size_t)node * WIDTH + lane * 8);
    float rr[8] = {bfl(rv.x), bfh(rv.x), bfl(rv.y), bfh(rv.y),
                   bfl(rv.z), bfh(rv.z), bfl(rv.w), bfh(rv.w)};
    f4_t b0 = *(const f4_t*)(bias + lane * 8);
    f4_t b1 = *(const f4_t*)(bias + lane * 8 + 4);
    float o[8];
    #pragma unroll
    for (int j = 0; j < 8; ++j) {
        float bj = (j < 4) ? b0[j] : b1[j - 4];
        float v = (a0[j] + a1[j]) * inv + rr[j] + bj;
        o[j] = RELU ? fmaxf(v, 0.f) : v;
    }
    uint4 w;
    w.x = (unsigned)f2bf(o[0]) | ((unsigned)f2bf(o[1]) << 16);
    w.y = (unsigned)f2bf(o[2]) | ((unsigned)f2bf(o[3]) << 16);
    w.z = (unsigned)f2bf(o[4]) | ((unsigned)f2bf(o[5]) << 16);
    w.w = (unsigned)f2bf(o[6]) | ((unsigned)f2bf(o[7]) << 16);
    *(uint4*)(hout + (size_t)node * WIDTH + lane * 8) = w;
}

// ---------------- edge scoring: 8 lanes x 8 bf16, 2 edges per group ----------------
__device__ __forceinline__ float dot8(uint4 va, uint4 vb) {
    return bfl(va.x) * bfl(vb.x) + bfh(va.x) * bfh(vb.x)
         + bfl(va.y) * bfl(vb.y) + bfh(va.y) * bfh(vb.y)
         + bfl(va.z) * bfl(vb.z) + bfh(va.z) * bfh(vb.z)
         + bfl(va.w) * bfl(vb.w) + bfh(va.w) * bfh(vb.w);
}

__global__ void score_k(const unsigned short* __restrict__ h2b, const int* __restrict__ pos,
                        const int* __restrict__ neg, float* __restrict__ out) {
    int t = blockIdx.x * 256 + threadIdx.x;
    int g = t >> 3, l = t & 7;
    int eg0 = g * 2;
    if (eg0 >= 2 * EPE) return;
    int eg1 = eg0 + 1;
    int a0i, b0i, a1i, b1i;
    if (eg0 < EPE) { a0i = pos[eg0]; b0i = pos[EPE + eg0]; }
    else { int e2 = eg0 - EPE; a0i = neg[e2]; b0i = neg[EPE + e2]; }
    if (eg1 < EPE) { a1i = pos[eg1]; b1i = pos[EPE + eg1]; }
    else { int e2 = eg1 - EPE; a1i = neg[e2]; b1i = neg[EPE + e2]; }
    const unsigned short* hb = h2b + (size_t)l * 8;
    uint4 va0 = *(const uint4*)(hb + (size_t)a0i * 64);
    uint4 vb0 = *(const uint4*)(hb + (size_t)b0i * 64);
    uint4 va1 = *(const uint4*)(hb + (size_t)a1i * 64);
    uint4 vb1 = *(const uint4*)(hb + (size_t)b1i * 64);
    float p0 = dot8(va0, vb0);
    float p1 = dot8(va1, vb1);
    p0 += __shfl_xor(p0, 1, 8);
    p1 += __shfl_xor(p1, 1, 8);
    p0 += __shfl_xor(p0, 2, 8);
    p1 += __shfl_xor(p1, 2, 8);
    p0 += __shfl_xor(p0, 4, 8);
    p1 += __shfl_xor(p1, 4, 8);
    if (l == 0) { out[eg0] = p0; out[eg1] = p1; }
}

extern "C" void kernel_launch(void* const* d_in, const int* in_sizes, int n_in,
                              void* d_out, int out_size, void* d_ws, size_t ws_size,
                              hipStream_t stream) {
    const float* x   = (const float*)d_in[0];
    const int*   ei  = (const int*)d_in[1];
    const int*   pei = (const int*)d_in[2];
    const int*   nei = (const int*)d_in[3];
    const float* Wl0 = (const float*)d_in[4];
    const float* bl0 = (const float*)d_in[5];
    const float* Wr0 = (const float*)d_in[6];
    const float* Wl1 = (const float*)d_in[7];
    const float* bl1 = (const float*)d_in[8];
    const float* Wr1 = (const float*)d_in[9];
    float* out = (float*)d_out;

    char* ws = (char*)d_ws;
    size_t off = 0;
    auto alloc = [&](size_t bytes) {
        void* p = ws + off;
        off = (off + bytes + 255) & ~(size_t)255;
        return p;
    };
    float* invd     = (float*)alloc((size_t)NN * 4);
    int*   row_ptr  = (int*)  alloc((size_t)(NN + 1) * 4);
    int*   bin_cnt  = (int*)  alloc((size_t)NBINS * 4);
    int*   binbuf   = (int*)  alloc((size_t)NBINS * BCAP * 4);
    int*   csr      = (int*)  alloc((size_t)EE * 4);
    unsigned short* Bp0 = (unsigned short*)alloc((size_t)4096 * 8 * 2);
    unsigned short* Bp1 = (unsigned short*)alloc((size_t)2048 * 8 * 2);
    float* b0p = (float*)alloc(128 * 4);
    float* b1p = (float*)alloc(64 * 4);
    unsigned short* t0  = (unsigned short*)alloc((size_t)NN * 128 * 2);  // reused as t1
    unsigned short* r0b = (unsigned short*)alloc((size_t)NN * 128 * 2);  // reused as r1b
    unsigned short* h1b = (unsigned short*)alloc((size_t)NN * 128 * 2);  // reused as h2b
    unsigned short* t1  = t0;
    unsigned short* r1b = r0b;
    unsigned short* h2b = h1b;

    const int* src = ei;        // edge_index[0]
    const int* dst = ei + EE;   // edge_index[1]

    hipMemsetAsync(bin_cnt, 0, (size_t)NBINS * 4, stream);

    // binned CSR build (scan folded into pass 2)
    binpass1_k<<<NB1, 256, 0, stream>>>(src, dst, bin_cnt, binbuf);
    binpass2_k<<<NBINS, 256, 0, stream>>>(binbuf, bin_cnt, csr, row_ptr, invd);

    // weight + bias packing (single kernel)
    pack_k<<<25, 256, 0, stream>>>(Wl0, Wr0, Wl1, Wr1, bl0, bl1, Bp0, Bp1, b0p, b1p);

    // layer 0: [t0 | r0] = x @ [Wl0 | Wr0]; h1 = relu(mean(t0) + r0 + b0)
    gemm_k<256, 128, true><<<1563, 256, 0, stream>>>(x, Bp0, t0, r0b);
    gather_fuse_k<4, 128, true><<<(NN * 16 + 255) / 256, 256, 0, stream>>>(
        t0, csr, row_ptr, invd, r0b, b0p, h1b);

    // layer 1: [t1 | r1] = h1 @ [Wl1 | Wr1]; h2 = mean(t1) + r1 + b1
    gemm_k<128, 64, false><<<1563, 256, 0, stream>>>(h1b, Bp1, t1, r1b);
    gather_fuse_k<3, 64, false><<<(NN * 8 + 255) / 256, 256, 0, stream>>>(
        t1, csr, row_ptr, invd, r1b, b1p, h2b);

    // scoring (2 edges per 8-lane group)
    score_k<<<(EPE * 8 + 255) / 256, 256, 0, stream>>>(h2b, pei, nei, out);
}